// Round 4
// baseline (442.037 us; speedup 1.0000x reference)
//
#include <hip/hip_runtime.h>
#include <cstddef>

#define THRESH_V 10.0f
#define RPB 4  // rows per block: one wave (64 lanes) per row

// symmetric-extension read: k in [-6, n+6]
static __device__ __forceinline__ float symread(const float* s, int k, int n) {
  int idx = (k < 0) ? (-1 - k) : ((k >= n) ? (2 * n - 1 - k) : k);
  return s[idx];
}

// forward DWT stage: src[n] -> ca[m], cd[m] (cd hard-thresholded), m = (n+7)/2
// y[i] = sum_{t=0..7} ext[2i+t] * filt[7-t].
// Accumulation model: numpy pairwise .sum(-1) over an 8-wide product window:
//   p_t = fl(v_t * w_t)                  (each product rounded, NO fma)
//   y   = ((p0+p1)+(p2+p3)) + ((p4+p5)+(p6+p7))   (fixed tree)
// This is numpy's pairwise_sum for n==8 — the natural vectorized np translation
// (sliding windows * reversed filter, then .sum(-1)). Applied to BOTH cA and cD
// since cA feeds later levels' threshold decisions.
// fp contract must be OFF or clang re-fuses mul+add into FMA and changes rounding.
static __device__ __forceinline__ void fwd_stage(const float* __restrict__ src, int n,
                                                 float* __restrict__ ca,
                                                 float* __restrict__ cd, int lane) {
#pragma clang fp contract(off)
  // reversed filters: R*[t] = DEC_*[7-t]
  const float RLO[8] = {  0.0322231006040427f,   -0.012603967262037833f,
                         -0.09921954357684722f,   0.29785779560527736f,
                          0.8037387518059161f,    0.49761866763201545f,
                         -0.02963552764599851f,  -0.07576571478927333f };
  const float RHI[8] = { -0.07576571478927333f,   0.02963552764599851f,
                          0.49761866763201545f,  -0.8037387518059161f,
                          0.29785779560527736f,   0.09921954357684722f,
                         -0.012603967262037833f, -0.0322231006040427f };
  const int m = (n + 7) >> 1;
  for (int i = lane; i < m; i += 64) {
    const int kb = 2 * i - 6;
    float v[8];
#pragma unroll
    for (int t = 0; t < 8; ++t) v[t] = symread(src, kb + t, n);

    float pl[8], ph[8];
#pragma unroll
    for (int t = 0; t < 8; ++t) { pl[t] = v[t] * RLO[t]; ph[t] = v[t] * RHI[t]; }

    const float sLo = ((pl[0] + pl[1]) + (pl[2] + pl[3])) +
                      ((pl[4] + pl[5]) + (pl[6] + pl[7]));
    const float sHi = ((ph[0] + ph[1]) + (ph[2] + ph[3])) +
                      ((ph[4] + ph[5]) + (ph[6] + ph[7]));

    ca[i] = sLo;
    // hard threshold: keep small coefficients, zero large ones
    cd[i] = (fabsf(sHi) <= THRESH_V) ? sHi : 0.f;
  }
}

// inverse DWT stage (fp32, no decisions — 0.81 tolerance dwarfs rounding noise):
// rec[q] = sum_{p=0..3} ca[j0+p]*LO[tb+2p] + sum_p cd[j0+p]*HI[tb+2p],
// j0=q>>1, tb=(q&1)?0:1; outLen <= 2n-6 keeps all indices in range.
static __device__ __forceinline__ void inv_stage(const float* __restrict__ ca,
                                                 const float* __restrict__ cd,
                                                 float* __restrict__ dst, int outLen,
                                                 int lane) {
#pragma clang fp contract(off)
  const float LO[8] = { -0.07576571478927333f,  -0.02963552764599851f,
                         0.49761866763201545f,   0.8037387518059161f,
                         0.29785779560527736f,  -0.09921954357684722f,
                        -0.012603967262037833f,  0.0322231006040427f };
  const float HI[8] = { -0.0322231006040427f,   -0.012603967262037833f,
                         0.09921954357684722f,   0.29785779560527736f,
                        -0.8037387518059161f,    0.49761866763201545f,
                         0.02963552764599851f,  -0.07576571478927333f };
  for (int q = lane; q < outLen; q += 64) {
    const int j0 = q >> 1;
    const int tb = (q & 1) ? 0 : 1;
    float sA = 0.f, sD = 0.f;
#pragma unroll
    for (int p = 0; p < 4; ++p) {
      sA = sA + ca[j0 + p] * LO[tb + 2 * p];
      sD = sD + cd[j0 + p] * HI[tb + 2 * p];
    }
    dst[q] = sA + sD;
  }
}

// One wave per row; whole DWT/IDWT pipeline in a private LDS slice.
// LDS slice layout (floats): sx[512] | sA[259] | sB[259] | d1[259] | d2[133] | d3[70] | d4[38]
__global__ __launch_bounds__(256) void wavelet_denoise_kernel(
    const float* __restrict__ x, float* __restrict__ out, int nrows) {
  __shared__ float lds[RPB][1536];  // 24576 B/block -> 6 blocks/CU (24 waves)
  const int wave = threadIdx.x >> 6;
  const int lane = threadIdx.x & 63;
  const int row = blockIdx.x * RPB + wave;
  const bool act = row < nrows;

  float* S  = lds[wave];
  float* sx = S;          // 512
  float* sA = S + 512;    // 259
  float* sB = S + 771;    // 259
  float* d1 = S + 1030;   // 259
  float* d2 = S + 1289;   // 133
  float* d3 = S + 1422;   // 70
  float* d4 = S + 1492;   // 38 (ends at 1530)

  // load row: 512 floats via float4 (2 KB, coalesced 16B/lane)
  if (act) {
    const float4* src4 = reinterpret_cast<const float4*>(x + (size_t)row * 512);
    float4* dst4 = reinterpret_cast<float4*>(sx);
    for (int c = lane; c < 128; c += 64) dst4[c] = src4[c];
  }
  __syncthreads();

  // analysis: 512 -> 259 -> 133 -> 70 -> 38
  if (act) fwd_stage(sx, 512, sA, d1, lane);   // ca1 in sA
  __syncthreads();
  if (act) fwd_stage(sA, 259, sB, d2, lane);   // ca2 in sB
  __syncthreads();
  if (act) fwd_stage(sB, 133, sA, d3, lane);   // ca3 in sA[0..69]
  __syncthreads();
  if (act) fwd_stage(sA, 70, sB, d4, lane);    // ca4 in sB[0..37]
  __syncthreads();

  // synthesis: 38 -> 70 -> 133 -> 259 -> 512 (truncations folded into outLen)
  if (act) inv_stage(sB, d4, sA, 70, lane);    // rec70
  __syncthreads();
  if (act) inv_stage(sA, d3, sB, 133, lane);   // rec133 (2*70-6=134 truncated)
  __syncthreads();
  if (act) inv_stage(sB, d2, sA, 259, lane);   // rec259 (260 truncated)
  __syncthreads();
  if (act) inv_stage(sA, d1, out + (size_t)row * 512, 512, lane);  // final to global
}

extern "C" void kernel_launch(void* const* d_in, const int* in_sizes, int n_in,
                              void* d_out, int out_size, void* d_ws, size_t ws_size,
                              hipStream_t stream) {
  const float* x = (const float*)d_in[0];  // (nrows, 512) fp32
  float* out = (float*)d_out;              // (nrows, 512) fp32
  const int nrows = in_sizes[0] / 512;
  const int grid = (nrows + RPB - 1) / RPB;
  wavelet_denoise_kernel<<<dim3(grid), dim3(256), 0, stream>>>(x, out, nrows);
}